// Round 4
// baseline (643.215 us; speedup 1.0000x reference)
//
#include <hip/hip_runtime.h>
#include <hip/hip_bf16.h>

#define N_NODES 100000
#define N_EDGES 1600000
#define F_IN_DIM 100
#define F_IN_PAD 104     // padded bf16 row stride (13 x 16B chunks)
#define H_DIM 256
#define BN_DIM 128
#define N_LABELS 19
#define BN_EPS 1e-5f
#define M_PAD 100096     // 782 * 128, guard-free row padding for fc GEMMs

// bucket-partitioned CSR build
#define BUCKET_SHIFT 8
#define NB 391           // ceil(100000 / 256) buckets of 256 nodes
#define EPB 4096         // edges per partition block
#define PB 391           // ceil(1600000 / 4096) partition blocks

typedef __attribute__((ext_vector_type(8))) short bf16x8;   // 4 VGPRs, MFMA A/B frag / 16B
typedef __attribute__((ext_vector_type(4))) short s16x4;    // 8B
typedef __attribute__((ext_vector_type(4))) float f32x4;    // MFMA C/D frag

static __device__ inline short f2bf(float f) {
    __hip_bfloat16 h = __float2bfloat16(f);
    return *(short*)&h;
}
static __device__ inline float bf2f(short s) {
    unsigned u = ((unsigned)(unsigned short)s) << 16;
    return __builtin_bit_cast(float, u);
}

// async global->LDS DMA, 16B per lane; LDS dest = wave-uniform base + lane*16
#define GLOAD_LDS16(g, l) \
    __builtin_amdgcn_global_load_lds((__attribute__((address_space(1))) const unsigned int*)(g), \
                                     (__attribute__((address_space(3))) unsigned int*)(l), 16, 0, 0)

// ---------------------------------------------------------------- CSR build (bucketed)
__global__ __launch_bounds__(256) void part_hist_kernel(const int* __restrict__ dst,
                                                        int* __restrict__ part_hist, int E)
{
    __shared__ int h[NB];
    int tid = threadIdx.x;
    for (int i = tid; i < NB; i += 256) h[i] = 0;
    __syncthreads();
    int base = blockIdx.x * EPB;
    int end = min(base + EPB, E);
    for (int e = base + tid; e < end; e += 256)
        atomicAdd(&h[dst[e] >> BUCKET_SHIFT], 1);
    __syncthreads();
    for (int i = tid; i < NB; i += 256) part_hist[blockIdx.x * NB + i] = h[i];
}

__global__ __launch_bounds__(512) void bucket_total_kernel(const int* __restrict__ part_hist,
                                                           int* __restrict__ bucket_total)
{
    __shared__ int ls[512];
    int b = blockIdx.x;
    int s = 0;
    for (int p = threadIdx.x; p < PB; p += 512) s += part_hist[p * NB + b];
    ls[threadIdx.x] = s;
    __syncthreads();
    for (int off = 256; off > 0; off >>= 1) {
        if (threadIdx.x < off) ls[threadIdx.x] += ls[threadIdx.x + off];
        __syncthreads();
    }
    if (threadIdx.x == 0) bucket_total[b] = ls[0];
}

__global__ __launch_bounds__(512) void bucket_scan_kernel(const int* __restrict__ bucket_total,
                                                          int* __restrict__ bucket_base)
{
    __shared__ int ls[512];
    int tid = threadIdx.x;
    ls[tid] = (tid < NB) ? bucket_total[tid] : 0;
    __syncthreads();
    for (int off = 1; off < 512; off <<= 1) {
        int v = ls[tid];
        int add = (tid >= off) ? ls[tid - off] : 0;
        __syncthreads();
        ls[tid] = v + add;
        __syncthreads();
    }
    if (tid < NB) bucket_base[tid] = (tid > 0) ? ls[tid - 1] : 0;
    if (tid == 0) bucket_base[NB] = ls[NB - 1];
}

__global__ __launch_bounds__(512) void part_offset_kernel(int* __restrict__ part_hist,
                                                          const int* __restrict__ bucket_base)
{
    __shared__ int ls[512];
    int b = blockIdx.x;
    int tid = threadIdx.x;
    int v = (tid < PB) ? part_hist[tid * NB + b] : 0;
    ls[tid] = v;
    __syncthreads();
    for (int off = 1; off < 512; off <<= 1) {
        int x = ls[tid];
        int add = (tid >= off) ? ls[tid - off] : 0;
        __syncthreads();
        ls[tid] = x + add;
        __syncthreads();
    }
    if (tid < PB) part_hist[tid * NB + b] = bucket_base[b] + ((tid > 0) ? ls[tid - 1] : 0);
}

__global__ __launch_bounds__(256) void partition_kernel(const int* __restrict__ src,
                                                        const int* __restrict__ dst,
                                                        const int* __restrict__ part_hist,
                                                        int* __restrict__ ep, int E)
{
    __shared__ int cur[NB];
    int tid = threadIdx.x;
    for (int i = tid; i < NB; i += 256) cur[i] = part_hist[blockIdx.x * NB + i];
    __syncthreads();
    int base = blockIdx.x * EPB;
    int end = min(base + EPB, E);
    for (int e = base + tid; e < end; e += 256) {
        int d = dst[e];
        int s = src[e];
        int pos = atomicAdd(&cur[d >> BUCKET_SHIFT], 1);
        ep[pos] = (s << 8) | (d & 255);
    }
}

__global__ __launch_bounds__(256) void bucket_csr_kernel(const int* __restrict__ ep,
                                                         const int* __restrict__ bucket_base,
                                                         int* __restrict__ row_start,
                                                         float* __restrict__ dinv,
                                                         int* __restrict__ src_sorted, int N, int E)
{
    __shared__ int h[256], sc[256], cur[256];
    int b = blockIdx.x;
    int tid = threadIdx.x;
    int e0 = bucket_base[b], e1 = bucket_base[b + 1];
    int node0 = b << BUCKET_SHIFT;
    int nn = min(256, N - node0);

    h[tid] = 0;
    __syncthreads();
    for (int e = e0 + tid; e < e1; e += 256)
        atomicAdd(&h[ep[e] & 255], 1);
    __syncthreads();

    sc[tid] = h[tid];
    __syncthreads();
    for (int off = 1; off < 256; off <<= 1) {
        int v = sc[tid];
        int add = (tid >= off) ? sc[tid - off] : 0;
        __syncthreads();
        sc[tid] = v + add;
        __syncthreads();
    }
    int excl = e0 + ((tid > 0) ? sc[tid - 1] : 0);
    if (tid < nn) {
        row_start[node0 + tid] = excl;
        dinv[node0 + tid] = rsqrtf((float)h[tid] + 1.0f);
    }
    cur[tid] = excl;
    __syncthreads();
    for (int e = e0 + tid; e < e1; e += 256) {
        int p = ep[e];
        int pos = atomicAdd(&cur[p & 255], 1);
        src_sorted[pos] = ((unsigned)p) >> 8;
    }
    if (b == 0 && tid == 0) row_start[N] = E;
}

// ---------------------------------------------------------------- weight pack (all 5 in one)
__global__ __launch_bounds__(256) void pack_all(
    const float* __restrict__ W1, const float* __restrict__ W2, const float* __restrict__ W3,
    const float* __restrict__ Wf1, const float* __restrict__ Wf2a,
    short* __restrict__ Wt1, short* __restrict__ Wt2, short* __restrict__ Wt3,
    short* __restrict__ Wtf1, short* __restrict__ Wtf2a)
{
    int idx = blockIdx.x * 256 + threadIdx.x;
    const float* W; short* Wt; int K, N, Kp, local;
    if (idx < 10400)       { W = W1;   Wt = Wt1;   K = 100; N = 100; Kp = 104; local = idx; }
    else if (idx < 20800)  { W = W2;   Wt = Wt2;   K = 100; N = 100; Kp = 104; local = idx - 10400; }
    else if (idx < 47424)  { W = W3;   Wt = Wt3;   K = 100; N = 256; Kp = 104; local = idx - 20800; }
    else if (idx < 112960) { W = Wf1;  Wt = Wtf1;  K = 256; N = 256; Kp = 256; local = idx - 47424; }
    else if (idx < 145728) { W = Wf2a; Wt = Wtf2a; K = 256; N = 128; Kp = 256; local = idx - 112960; }
    else return;
    int n = local / Kp, k = local - n * Kp;
    Wt[local] = (k < K) ? f2bf(W[(size_t)k * N + n]) : (short)0;
}

// ---------------------------------------------------------------- one-shot MFMA GEMM (K<=104)
template<int ABF16>
__global__ __launch_bounds__(256) void gemm_oneshot(
    const void* __restrict__ Av, const short* __restrict__ Wt,
    const float* __restrict__ bias, const float* __restrict__ rowscale,
    short* __restrict__ C, int M, int Nout, int strideA, int strideC, int relu)
{
    __shared__ __align__(16) short As[128][F_IN_PAD];
    __shared__ __align__(16) short Bs[128][F_IN_PAD];
    int tid = threadIdx.x;
    int rowBase = blockIdx.x * 128;
    int colBase = blockIdx.y * 128;

    if (ABF16) {
        const short* A = (const short*)Av;
        for (int ch = tid; ch < 128 * 13; ch += 256) {
            int r = ch / 13, c8 = (ch - r * 13) * 8;
            int gr = rowBase + r;
            bf16x8 o = (bf16x8){0,0,0,0,0,0,0,0};
            if (gr < M) o = *(const bf16x8*)(A + (size_t)gr * strideA + c8);
            *(bf16x8*)(&As[r][c8]) = o;
        }
    } else {
        const float* A = (const float*)Av;
        for (int ch = tid; ch < 128 * 25; ch += 256) {
            int r = ch / 25, c4 = (ch - r * 25) * 4;
            int gr = rowBase + r;
            float4 v = make_float4(0.f, 0.f, 0.f, 0.f);
            if (gr < M) v = *(const float4*)(A + (size_t)gr * strideA + c4);
            v.x = fminf(fmaxf(v.x, -0.4f), 0.4f);
            v.y = fminf(fmaxf(v.y, -0.4f), 0.4f);
            v.z = fminf(fmaxf(v.z, -0.4f), 0.4f);
            v.w = fminf(fmaxf(v.w, -0.4f), 0.4f);
            s16x4 o = (s16x4){f2bf(v.x), f2bf(v.y), f2bf(v.z), f2bf(v.w)};
            *(s16x4*)(&As[r][c4]) = o;
        }
        for (int r = tid; r < 128; r += 256)     // zero pad cols 100..103
            *(s16x4*)(&As[r][100]) = (s16x4){0, 0, 0, 0};
    }
    for (int ch = tid; ch < 128 * 13; ch += 256) {
        int n = ch / 13, c8 = (ch - n * 13) * 8;
        int gn = colBase + n;
        bf16x8 o = (bf16x8){0,0,0,0,0,0,0,0};
        if (gn < Nout) o = *(const bf16x8*)(Wt + (size_t)gn * F_IN_PAD + c8);
        *(bf16x8*)(&Bs[n][c8]) = o;
    }
    __syncthreads();   // the only barrier

    int wid = tid >> 6;
    int lane = tid & 63;
    int quad = lane >> 4, l15 = lane & 15;
    int wave_m = (wid & 1) * 64;
    int wave_n = (wid >> 1) * 64;

    f32x4 acc[4][4];
    #pragma unroll
    for (int i = 0; i < 4; i++)
        #pragma unroll
        for (int j = 0; j < 4; j++)
            acc[i][j] = (f32x4){0.f, 0.f, 0.f, 0.f};

    #pragma unroll
    for (int kc = 0; kc < 4; kc++) {
        int off = kc * 32 + quad * 8;
        bool ok = (off + 8 <= F_IN_PAD);     // false only for kc=3, quad>=1 (pad)
        bf16x8 a[4], b[4];
        #pragma unroll
        for (int im = 0; im < 4; im++)
            a[im] = ok ? *(const bf16x8*)(&As[wave_m + im * 16 + l15][off])
                       : (bf16x8){0,0,0,0,0,0,0,0};
        #pragma unroll
        for (int in = 0; in < 4; in++)
            b[in] = ok ? *(const bf16x8*)(&Bs[wave_n + in * 16 + l15][off])
                       : (bf16x8){0,0,0,0,0,0,0,0};
        #pragma unroll
        for (int im = 0; im < 4; im++)
            #pragma unroll
            for (int in = 0; in < 4; in++)
                acc[im][in] = __builtin_amdgcn_mfma_f32_16x16x32_bf16(
                    a[im], b[in], acc[im][in], 0, 0, 0);
    }

    // ---- epilogue: C/D layout col=lane&15, row=quad*4+reg
    #pragma unroll
    for (int im = 0; im < 4; im++) {
        #pragma unroll
        for (int reg = 0; reg < 4; reg++) {
            int row = rowBase + wave_m + im * 16 + quad * 4 + reg;
            if (row >= M) continue;
            float rs = rowscale ? rowscale[row] : 1.f;
            #pragma unroll
            for (int in = 0; in < 4; in++) {
                int col = colBase + wave_n + in * 16 + l15;
                if (col >= strideC) continue;
                float v = 0.f;
                if (col < Nout) {
                    v = acc[im][in][reg];
                    if (bias) v += bias[col];
                    v *= rs;
                    if (relu) v = fmaxf(v, 0.f);
                }
                C[(size_t)row * strideC + col] = f2bf(v);
            }
        }
    }
}

// ---------------------------------------------------------------- fused fc1 + fc2a (v3)
// v2 structure (async-LDS A staging + swizzle, swapped GEMM1, Hs overwrite, GEMM2)
// plus FUSED BN partial stats: the 128x128 output tile is in registers; reduce
// (masked to row < N_NODES) into the dead SB buffer, then 2 global atomics/col/block.
// Replaces the separate bn_stats kernel (25MB re-read + launch).
__global__ __launch_bounds__(512, 4) void fc_fused_kernel(
    const short* __restrict__ A,      // [M_PAD][256] bf16
    const short* __restrict__ W1t,    // [256][256] bf16, n-major
    const float* __restrict__ b1v,
    const short* __restrict__ W2t,    // [128][256] bf16, n-major
    const float* __restrict__ b2v,
    short* __restrict__ C,            // [M_PAD][128] bf16
    float* __restrict__ bn_sum, float* __restrict__ bn_sumsq)
{
    __shared__ __align__(16) short SB[128 * 256];   // 64 KB: As, then Hs, then stat scratch
    int tid = threadIdx.x;
    int wid = tid >> 6;
    int lane = tid & 63;
    int quad = lane >> 4, l15 = lane & 15;
    int rowBase = blockIdx.x * 128;
    int xr = (l15 & 7) << 4;          // byte-XOR for this lane's rows (row&7 == l15&7)

    // ---- stage A strip: 64 chunks x 1KB, chunk c = rows {2c, 2c+1}; source pre-swizzled
    #pragma unroll
    for (int i = 0; i < 8; i++) {
        int c = i * 8 + wid;
        int r = c * 2 + (lane >> 5);
        int pb = ((lane & 31) * 16) ^ ((r & 7) << 4);   // swizzled byte-in-row
        const short* gp = A + (size_t)(rowBase + r) * H_DIM + (pb >> 1);
        GLOAD_LDS16(gp, SB + c * 512);
    }

    int wm = (wid & 1) * 64;          // GEMM1: 2M x 4N waves, 64x64 tile each
    int wn = (wid >> 1) * 64;

    f32x4 acc[4][4];
    #pragma unroll
    for (int i = 0; i < 4; i++)
        #pragma unroll
        for (int j = 0; j < 4; j++)
            acc[i][j] = (f32x4){0.f, 0.f, 0.f, 0.f};

    bf16x8 bA[4], bB[4];
    auto g1loadB = [&](bf16x8 (&dst)[4], int ks) {
        #pragma unroll
        for (int in = 0; in < 4; in++)
            dst[in] = *(const bf16x8*)(W1t + (size_t)(wn + in * 16 + l15) * H_DIM
                                       + ks * 32 + quad * 8);
    };
    auto g1step = [&](bf16x8 (&bc)[4], int ks) {
        bf16x8 a_[4];
        #pragma unroll
        for (int im = 0; im < 4; im++)
            a_[im] = *(const bf16x8*)(SB + (wm + im * 16 + l15) * 256
                                      + (((ks * 64 + quad * 16) ^ xr) >> 1));
        #pragma unroll
        for (int im = 0; im < 4; im++)
            #pragma unroll
            for (int in = 0; in < 4; in++)   // swapped: lane -> m=l15-based, 4 consecutive n
                acc[im][in] = __builtin_amdgcn_mfma_f32_16x16x32_bf16(
                    bc[in], a_[im], acc[im][in], 0, 0, 0);
    };

    g1loadB(bA, 0);        // prefetch ks=0 before the staging barrier
    __syncthreads();       // vmcnt(0): A staging complete

    g1loadB(bB, 1); g1step(bA, 0);
    g1loadB(bA, 2); g1step(bB, 1);
    g1loadB(bB, 3); g1step(bA, 2);
    g1loadB(bA, 4); g1step(bB, 3);
    g1loadB(bB, 5); g1step(bA, 4);
    g1loadB(bA, 6); g1step(bB, 5);
    g1loadB(bB, 7); g1step(bA, 6);
    g1step(bB, 7);

    // bias for swapped layout: n = wn + in*16 + quad*4 + reg
    float bb1[4][4];
    #pragma unroll
    for (int in = 0; in < 4; in++)
        #pragma unroll
        for (int r = 0; r < 4; r++)
            bb1[in][r] = b1v[wn + in * 16 + quad * 4 + r];

    __syncthreads();       // all waves done READING As -> safe to overwrite as Hs

    // GEMM2 prefetch (global, independent of LDS) issued before the Hs writes
    int wm2 = (wid & 1) * 64;         // GEMM2: 2M x 4N waves, 64x32 tile each
    int wn2 = (wid >> 1) * 32;
    bf16x8 cA[2], cB[2];
    auto g2loadB = [&](bf16x8 (&dst)[2], int ks) {
        #pragma unroll
        for (int in = 0; in < 2; in++)
            dst[in] = *(const bf16x8*)(W2t + (size_t)(wn2 + in * 16 + l15) * H_DIM
                                       + ks * 32 + quad * 8);
    };
    g2loadB(cA, 0);
    float bb2[2] = { b2v[wn2 + l15], b2v[wn2 + 16 + l15] };

    // ---- Hs write: relu(acc+b1) -> bf16, packed 4-consecutive-n b64, swizzled
    #pragma unroll
    for (int im = 0; im < 4; im++) {
        int ml = wm + im * 16 + l15;
        #pragma unroll
        for (int in = 0; in < 4; in++) {
            int nb = (wn + in * 16 + quad * 4) * 2;     // byte offset of col group
            s16x4 o = (s16x4){
                f2bf(fmaxf(acc[im][in][0] + bb1[in][0], 0.f)),
                f2bf(fmaxf(acc[im][in][1] + bb1[in][1], 0.f)),
                f2bf(fmaxf(acc[im][in][2] + bb1[in][2], 0.f)),
                f2bf(fmaxf(acc[im][in][3] + bb1[in][3], 0.f))};
            *(s16x4*)(SB + ml * 256 + ((nb ^ xr) >> 1)) = o;
        }
    }
    __syncthreads();       // Hs visible

    // ---- GEMM2: out = Hs @ W2 + b2 (unswapped; proven epilogue layout)
    f32x4 acc2[4][2];
    #pragma unroll
    for (int i = 0; i < 4; i++)
        #pragma unroll
        for (int j = 0; j < 2; j++)
            acc2[i][j] = (f32x4){0.f, 0.f, 0.f, 0.f};

    auto g2step = [&](bf16x8 (&bc)[2], int ks) {
        bf16x8 a_[4];
        #pragma unroll
        for (int im = 0; im < 4; im++)
            a_[im] = *(const bf16x8*)(SB + (wm2 + im * 16 + l15) * 256
                                      + (((ks * 64 + quad * 16) ^ xr) >> 1));
        #pragma unroll
        for (int im = 0; im < 4; im++)
            #pragma unroll
            for (int in = 0; in < 2; in++)
                acc2[im][in] = __builtin_amdgcn_mfma_f32_16x16x32_bf16(
                    a_[im], bc[in], acc2[im][in], 0, 0, 0);
    };

    g2loadB(cB, 1); g2step(cA, 0);
    g2loadB(cA, 2); g2step(cB, 1);
    g2loadB(cB, 3); g2step(cA, 2);
    g2loadB(cA, 4); g2step(cB, 3);
    g2loadB(cB, 5); g2step(cA, 4);
    g2loadB(cA, 6); g2step(cB, 5);
    g2loadB(cB, 7); g2step(cA, 6);
    g2step(cB, 7);

    // ---- epilogue: row = quad*4+reg (M), col = l15 (N); rows guard-free via M_PAD
    float st_s[2] = {0.f, 0.f}, st_ss[2] = {0.f, 0.f};
    #pragma unroll
    for (int im = 0; im < 4; im++) {
        #pragma unroll
        for (int reg = 0; reg < 4; reg++) {
            int row = rowBase + wm2 + im * 16 + quad * 4 + reg;
            bool live = (row < N_NODES);
            #pragma unroll
            for (int in = 0; in < 2; in++) {
                int col = wn2 + in * 16 + l15;
                short ob = f2bf(acc2[im][in][reg] + bb2[in]);
                C[(size_t)row * BN_DIM + col] = ob;
                if (live) {                       // BN stats on bf16-rounded stored value
                    float v = bf2f(ob);
                    st_s[in] += v;
                    st_ss[in] += v * v;
                }
            }
        }
    }

    // ---- fused BN partial reduction in recycled SB (all LDS reads done)
    float* red = (float*)SB;          // [0..127]=sum, [128..255]=sumsq
    __syncthreads();
    if (tid < 256) red[tid] = 0.f;
    __syncthreads();
    #pragma unroll
    for (int in = 0; in < 2; in++) {
        int col = wn2 + in * 16 + l15;
        atomicAdd(&red[col], st_s[in]);
        atomicAdd(&red[col + 128], st_ss[in]);
    }
    __syncthreads();
    if (tid < 128) {
        atomicAdd(&bn_sum[tid], red[tid]);
        atomicAdd(&bn_sumsq[tid], red[tid + 128]);
    }
}

// ---------------------------------------------------------------- gather aggregation (bf16)
// v4: unroll x8 (8 loads in flight/lane) + 4/2/1 cascade remainder (no serial drain),
// 32-bit row-offset math. MODEs as before.
template<int F, int STRIDE, int T, int MODE>
__global__ void gather_kernel(const short* __restrict__ xws,
                              const int* __restrict__ row_start,
                              const int* __restrict__ src_sorted,
                              const float* __restrict__ dinv,
                              const float* __restrict__ bias,
                              short* __restrict__ out, int n)
{
    constexpr int CHUNKS = STRIDE / 8;
    constexpr unsigned ROWB = STRIDE * 2;   // row stride in bytes
    int group = (blockIdx.x * blockDim.x + threadIdx.x) / T;
    int lane = threadIdx.x % T;
    if (group >= n || lane >= CHUNKS) return;
    int d = group;
    int e0 = row_start[d], e1 = row_start[d + 1];
    const char* base = (const char*)xws + lane * 16;

    float acc[8] = {}, acc2[8] = {};
    int e = e0;
    for (; e + 7 < e1; e += 8) {
        int s0 = src_sorted[e + 0], s1 = src_sorted[e + 1];
        int s2 = src_sorted[e + 2], s3 = src_sorted[e + 3];
        int s4 = src_sorted[e + 4], s5 = src_sorted[e + 5];
        int s6 = src_sorted[e + 6], s7 = src_sorted[e + 7];
        bf16x8 v0 = *(const bf16x8*)(base + (unsigned)s0 * ROWB);
        bf16x8 v1 = *(const bf16x8*)(base + (unsigned)s1 * ROWB);
        bf16x8 v2 = *(const bf16x8*)(base + (unsigned)s2 * ROWB);
        bf16x8 v3 = *(const bf16x8*)(base + (unsigned)s3 * ROWB);
        bf16x8 v4 = *(const bf16x8*)(base + (unsigned)s4 * ROWB);
        bf16x8 v5 = *(const bf16x8*)(base + (unsigned)s5 * ROWB);
        bf16x8 v6 = *(const bf16x8*)(base + (unsigned)s6 * ROWB);
        bf16x8 v7 = *(const bf16x8*)(base + (unsigned)s7 * ROWB);
        #pragma unroll
        for (int j = 0; j < 8; j++) {
            acc[j]  += (bf2f(v0[j]) + bf2f(v2[j])) + (bf2f(v4[j]) + bf2f(v6[j]));
            acc2[j] += (bf2f(v1[j]) + bf2f(v3[j])) + (bf2f(v5[j]) + bf2f(v7[j]));
        }
    }
    if (e + 3 < e1) {
        int s0 = src_sorted[e + 0], s1 = src_sorted[e + 1];
        int s2 = src_sorted[e + 2], s3 = src_sorted[e + 3];
        bf16x8 v0 = *(const bf16x8*)(base + (unsigned)s0 * ROWB);
        bf16x8 v1 = *(const bf16x8*)(base + (unsigned)s1 * ROWB);
        bf16x8 v2 = *(const bf16x8*)(base + (unsigned)s2 * ROWB);
        bf16x8 v3 = *(const bf16x8*)(base + (unsigned)s3 * ROWB);
        #pragma unroll
        for (int j = 0; j < 8; j++) {
            acc[j]  += bf2f(v0[j]) + bf2f(v2[j]);
            acc2[j] += bf2f(v1[j]) + bf2f(v3[j]);
        }
        e += 4;
    }
    if (e + 1 < e1) {
        int s0 = src_sorted[e + 0], s1 = src_sorted[e + 1];
        bf16x8 v0 = *(const bf16x8*)(base + (unsigned)s0 * ROWB);
        bf16x8 v1 = *(const bf16x8*)(base + (unsigned)s1 * ROWB);
        #pragma unroll
        for (int j = 0; j < 8; j++) {
            acc[j]  += bf2f(v0[j]);
            acc2[j] += bf2f(v1[j]);
        }
        e += 2;
    }
    if (e < e1) {
        int s0 = src_sorted[e];
        bf16x8 v0 = *(const bf16x8*)(base + (unsigned)s0 * ROWB);
        #pragma unroll
        for (int j = 0; j < 8; j++) acc[j] += bf2f(v0[j]);
    }

    bf16x8 xv = *(const bf16x8*)(base + (unsigned)d * ROWB);
    float di = dinv[d];
    int coff = lane * 8;
    bf16x8 o;
    #pragma unroll
    for (int j = 0; j < 8; j++) {
        int col = coff + j;
        float v = 0.f;
        if (col < F) {
            v = di * (acc[j] + acc2[j] + bf2f(xv[j]));
            if (MODE == 0) v = fmaxf(v + bias[col], 0.f);
            if (MODE == 1) v = di * fmaxf(v + bias[col], 0.f);
        }
        o[j] = f2bf(v);
    }
    *(bf16x8*)(out + (size_t)d * STRIDE + coff) = o;
}

// ---------------------------------------------------------------- BN finalize
__global__ void bn_finalize_kernel(const float* __restrict__ sum, const float* __restrict__ sumsq,
                                   const float* __restrict__ gamma, const float* __restrict__ beta,
                                   float* __restrict__ a, float* __restrict__ b, int Ntot)
{
    int c = threadIdx.x;
    float inv_n = 1.0f / (float)Ntot;
    float mu = sum[c] * inv_n;
    float var = sumsq[c] * inv_n - mu * mu;
    float ai = gamma[c] * rsqrtf(var + BN_EPS);
    a[c] = ai;
    b[c] = beta[c] - mu * ai;
}

// ---------------------------------------------------------------- fused BN-apply + fc2b + log_softmax
__global__ __launch_bounds__(256) void fc2b_fused_kernel(
    const short* __restrict__ h, const float* __restrict__ bn_a, const float* __restrict__ bn_b,
    const float* __restrict__ W, const float* __restrict__ bias,
    float* __restrict__ out, int Ntot)
{
    __shared__ float Ws[BN_DIM][N_LABELS + 1];
    __shared__ float as[BN_DIM], bs[BN_DIM];
    for (int i = threadIdx.x; i < BN_DIM * N_LABELS; i += 256) {
        int k = i / N_LABELS, j = i - k * N_LABELS;
        Ws[k][j] = W[i];
    }
    if (threadIdx.x < BN_DIM) {
        as[threadIdx.x] = bn_a[threadIdx.x];
        bs[threadIdx.x] = bn_b[threadIdx.x];
    }
    __syncthreads();

    int r = blockIdx.x * 256 + threadIdx.x;
    if (r >= Ntot) return;

    float acc[N_LABELS];
    #pragma unroll
    for (int j = 0; j < N_LABELS; j++) acc[j] = bias[j];

    const short* hr = h + (size_t)r * BN_DIM;
    #pragma unroll
    for (int k0 = 0; k0 < BN_DIM; k0 += 8) {
        bf16x8 hv = *(const bf16x8*)(hr + k0);
        #pragma unroll
        for (int t = 0; t < 8; t++) {
            float v = fmaxf(bf2f(hv[t]) * as[k0 + t] + bs[k0 + t], 0.f);
            #pragma unroll
            for (int j = 0; j < N_LABELS; j++)
                acc[j] = fmaf(v, Ws[k0 + t][j], acc[j]);
        }
    }

    float m = acc[0];
    #pragma unroll
    for (int j = 1; j < N_LABELS; j++) m = fmaxf(m, acc[j]);
    float s = 0.f;
    #pragma unroll
    for (int j = 0; j < N_LABELS; j++) s += expf(acc[j] - m);
    float lse = m + logf(s);
    float* o = out + (size_t)r * N_LABELS;
    #pragma unroll
    for (int j = 0; j < N_LABELS; j++) o[j] = acc[j] - lse;
}

// ================================================================ launch
extern "C" void kernel_launch(void* const* d_in, const int* in_sizes, int n_in,
                              void* d_out, int out_size, void* d_ws, size_t ws_size,
                              hipStream_t stream)
{
    const float* x      = (const float*)d_in[0];
    const int*   ei     = (const int*)d_in[1];
    const float* W1     = (const float*)d_in[2];
    const float* b1     = (const float*)d_in[3];
    const float* W2     = (const float*)d_in[4];
    const float* b2     = (const float*)d_in[5];
    const float* W3     = (const float*)d_in[6];
    const float* b3     = (const float*)d_in[7];
    const float* fc1_W  = (const float*)d_in[8];
    const float* fc1_b  = (const float*)d_in[9];
    const float* fc2aW  = (const float*)d_in[10];
    const float* fc2ab  = (const float*)d_in[11];
    const float* gamma  = (const float*)d_in[12];
    const float* beta   = (const float*)d_in[13];
    const float* fc2bW  = (const float*)d_in[14];
    const float* fc2bb  = (const float*)d_in[15];
    float* out = (float*)d_out;

    const int* src = ei;
    const int* dst = ei + N_EDGES;

    char* w = (char*)d_ws;
    float* dinv        = (float*)w;  w += ((size_t)N_NODES * 4 + 255) / 256 * 256;
    int*   row_start   = (int*)w;    w += ((size_t)(N_NODES + 1) * 4 + 255) / 256 * 256;
    int*   part_hist   = (int*)w;    w += ((size_t)PB * NB * 4 + 255) / 256 * 256;
    int*   bucket_total= (int*)w;    w += ((size_t)NB * 4 + 255) / 256 * 256;
    int*   bucket_base = (int*)w;    w += ((size_t)(NB + 1) * 4 + 255) / 256 * 256;
    float* bn_sum      = (float*)w;  w += 128 * 4;
    float* bn_sumsq    = (float*)w;  w += 128 * 4;
    float* bn_a        = (float*)w;  w += 128 * 4;
    float* bn_b        = (float*)w;  w += 128 * 4;
    short* Wt1         = (short*)w;  w += ((size_t)F_IN_DIM * F_IN_PAD * 2 + 255) / 256 * 256;
    short* Wt2         = (short*)w;  w += ((size_t)F_IN_DIM * F_IN_PAD * 2 + 255) / 256 * 256;
    short* Wt3         = (short*)w;  w += ((size_t)H_DIM * F_IN_PAD * 2 + 255) / 256 * 256;
    short* Wtf1        = (short*)w;  w += ((size_t)H_DIM * H_DIM * 2 + 255) / 256 * 256;
    short* Wtf2a       = (short*)w;  w += ((size_t)BN_DIM * H_DIM * 2 + 255) / 256 * 256;
    int*   src_sorted  = (int*)w;    w += ((size_t)N_EDGES * 4 + 255) / 256 * 256;
    int*   ep          = (int*)w;    w += ((size_t)N_EDGES * 4 + 255) / 256 * 256;
    short* xws100      = (short*)w;  w += ((size_t)N_NODES * F_IN_PAD * 2 + 255) / 256 * 256;
    short* agg100      = (short*)w;  w += ((size_t)N_NODES * F_IN_PAD * 2 + 255) / 256 * 256;
    short* big1        = (short*)w;  w += ((size_t)M_PAD * H_DIM * 2 + 255) / 256 * 256;
    short* big2        = (short*)w;  w += ((size_t)M_PAD * H_DIM * 2 + 255) / 256 * 256;

    // ---- CSR build (bucket-partitioned, LDS atomics) + dinv
    part_hist_kernel<<<PB, 256, 0, stream>>>(dst, part_hist, N_EDGES);
    bucket_total_kernel<<<NB, 512, 0, stream>>>(part_hist, bucket_total);
    bucket_scan_kernel<<<1, 512, 0, stream>>>(bucket_total, bucket_base);
    part_offset_kernel<<<NB, 512, 0, stream>>>(part_hist, bucket_base);
    partition_kernel<<<PB, 256, 0, stream>>>(src, dst, part_hist, ep, N_EDGES);
    bucket_csr_kernel<<<NB, 256, 0, stream>>>(ep, bucket_base, row_start, dinv,
                                              src_sorted, N_NODES, N_EDGES);

    // ---- pack weights (transpose + bf16 + zero-pad K), single launch
    pack_all<<<570, 256, 0, stream>>>(W1, W2, W3, fc1_W, fc2aW, Wt1, Wt2, Wt3, Wtf1, Wtf2a);

    const int nOne = (N_NODES + 127) / 128;   // 782
    int gatherBlocks = (N_NODES * 16 + 255) / 256;

    // ---- conv1: xw = clip(x) @ W1, rowscale dinv -> xws100; gather -> h1 (agg100)
    gemm_oneshot<0><<<dim3(nOne, 1), 256, 0, stream>>>(
        x, Wt1, nullptr, dinv, xws100, N_NODES, F_IN_DIM, F_IN_DIM, F_IN_PAD, 0);
    gather_kernel<F_IN_DIM, F_IN_PAD, 16, 0><<<gatherBlocks, 256, 0, stream>>>(
        xws100, row_start, src_sorted, dinv, b1, agg100, N_NODES);

    // ---- conv2: xw = h1 @ W2, rowscale dinv -> xws100; gather (postscale dinv) -> h2' (agg100)
    gemm_oneshot<1><<<dim3(nOne, 1), 256, 0, stream>>>(
        agg100, Wt2, nullptr, dinv, xws100, N_NODES, F_IN_DIM, F_IN_PAD, F_IN_PAD, 0);
    gather_kernel<F_IN_DIM, F_IN_PAD, 16, 1><<<gatherBlocks, 256, 0, stream>>>(
        xws100, row_start, src_sorted, dinv, b2, agg100, N_NODES);

    // ---- conv3 (aggregate-first): g = dinv_d*(sum h2' + self) -> xws100; h3 = relu(g@W3+b3) -> big1
    gather_kernel<F_IN_DIM, F_IN_PAD, 16, 2><<<gatherBlocks, 256, 0, stream>>>(
        agg100, row_start, src_sorted, dinv, nullptr, xws100, N_NODES);
    gemm_oneshot<1><<<dim3(nOne, 2), 256, 0, stream>>>(
        xws100, Wt3, b3, nullptr, big1, N_NODES, H_DIM, F_IN_PAD, H_DIM, 1);

    // ---- fused fc1 (256->256, relu) + fc2a (256->128) + BN stats: big1 -> big2
    hipMemsetAsync(bn_sum, 0, 2 * 128 * 4, stream);
    fc_fused_kernel<<<nOne, 512, 0, stream>>>(
        big1, Wtf1, fc1_b, Wtf2a, fc2ab, big2, bn_sum, bn_sumsq);

    bn_finalize_kernel<<<1, 128, 0, stream>>>(bn_sum, bn_sumsq, gamma, beta, bn_a, bn_b, N_NODES);

    // ---- fused BN-apply + fc2b + log_softmax -> out
    fc2b_fused_kernel<<<(N_NODES + 255) / 256, 256, 0, stream>>>(
        big2, bn_a, bn_b, fc2bW, fc2bb, out, N_NODES);
}

// Round 5
// 591.683 us; speedup vs baseline: 1.0871x; 1.0871x over previous
//
#include <hip/hip_runtime.h>
#include <hip/hip_bf16.h>

#define N_NODES 100000
#define N_EDGES 1600000
#define F_IN_DIM 100
#define F_IN_PAD 104     // padded bf16 row stride (13 x 16B chunks)
#define H_DIM 256
#define BN_DIM 128
#define N_LABELS 19
#define BN_EPS 1e-5f
#define M_PAD 100096     // 782 * 128, guard-free row padding for all node tables

// bucket-partitioned CSR build
#define BUCKET_SHIFT 8
#define NB 391           // ceil(100000 / 256) buckets of 256 nodes
#define EPB 4096         // edges per partition block
#define PB 391           // ceil(1600000 / 4096) partition blocks

typedef __attribute__((ext_vector_type(8))) short bf16x8;   // 4 VGPRs, MFMA A/B frag / 16B
typedef __attribute__((ext_vector_type(4))) short s16x4;    // 8B
typedef __attribute__((ext_vector_type(4))) float f32x4;    // MFMA C/D frag

static __device__ inline short f2bf(float f) {
    __hip_bfloat16 h = __float2bfloat16(f);
    return *(short*)&h;
}
static __device__ inline float bf2f(short s) {
    unsigned u = ((unsigned)(unsigned short)s) << 16;
    return __builtin_bit_cast(float, u);
}

// async global->LDS DMA, 16B per lane; LDS dest = wave-uniform base + lane*16
#define GLOAD_LDS16(g, l) \
    __builtin_amdgcn_global_load_lds((__attribute__((address_space(1))) const unsigned int*)(g), \
                                     (__attribute__((address_space(3))) unsigned int*)(l), 16, 0, 0)

// ---------------------------------------------------------------- CSR build (bucketed)
__global__ __launch_bounds__(256) void part_hist_kernel(const int* __restrict__ dst,
                                                        int* __restrict__ part_hist, int E)
{
    __shared__ int h[NB];
    int tid = threadIdx.x;
    for (int i = tid; i < NB; i += 256) h[i] = 0;
    __syncthreads();
    int base = blockIdx.x * EPB;
    int end = min(base + EPB, E);
    for (int e = base + tid; e < end; e += 256)
        atomicAdd(&h[dst[e] >> BUCKET_SHIFT], 1);
    __syncthreads();
    for (int i = tid; i < NB; i += 256) part_hist[blockIdx.x * NB + i] = h[i];
}

__global__ __launch_bounds__(512) void bucket_total_kernel(const int* __restrict__ part_hist,
                                                           int* __restrict__ bucket_total)
{
    __shared__ int ls[512];
    int b = blockIdx.x;
    int s = 0;
    for (int p = threadIdx.x; p < PB; p += 512) s += part_hist[p * NB + b];
    ls[threadIdx.x] = s;
    __syncthreads();
    for (int off = 256; off > 0; off >>= 1) {
        if (threadIdx.x < off) ls[threadIdx.x] += ls[threadIdx.x + off];
        __syncthreads();
    }
    if (threadIdx.x == 0) bucket_total[b] = ls[0];
}

__global__ __launch_bounds__(512) void bucket_scan_kernel(const int* __restrict__ bucket_total,
                                                          int* __restrict__ bucket_base)
{
    __shared__ int ls[512];
    int tid = threadIdx.x;
    ls[tid] = (tid < NB) ? bucket_total[tid] : 0;
    __syncthreads();
    for (int off = 1; off < 512; off <<= 1) {
        int v = ls[tid];
        int add = (tid >= off) ? ls[tid - off] : 0;
        __syncthreads();
        ls[tid] = v + add;
        __syncthreads();
    }
    if (tid < NB) bucket_base[tid] = (tid > 0) ? ls[tid - 1] : 0;
    if (tid == 0) bucket_base[NB] = ls[NB - 1];
}

__global__ __launch_bounds__(512) void part_offset_kernel(int* __restrict__ part_hist,
                                                          const int* __restrict__ bucket_base)
{
    __shared__ int ls[512];
    int b = blockIdx.x;
    int tid = threadIdx.x;
    int v = (tid < PB) ? part_hist[tid * NB + b] : 0;
    ls[tid] = v;
    __syncthreads();
    for (int off = 1; off < 512; off <<= 1) {
        int x = ls[tid];
        int add = (tid >= off) ? ls[tid - off] : 0;
        __syncthreads();
        ls[tid] = x + add;
        __syncthreads();
    }
    if (tid < PB) part_hist[tid * NB + b] = bucket_base[b] + ((tid > 0) ? ls[tid - 1] : 0);
}

__global__ __launch_bounds__(256) void partition_kernel(const int* __restrict__ src,
                                                        const int* __restrict__ dst,
                                                        const int* __restrict__ part_hist,
                                                        int* __restrict__ ep, int E)
{
    __shared__ int cur[NB];
    int tid = threadIdx.x;
    for (int i = tid; i < NB; i += 256) cur[i] = part_hist[blockIdx.x * NB + i];
    __syncthreads();
    int base = blockIdx.x * EPB;
    int end = min(base + EPB, E);
    for (int e = base + tid; e < end; e += 256) {
        int d = dst[e];
        int s = src[e];
        int pos = atomicAdd(&cur[d >> BUCKET_SHIFT], 1);
        ep[pos] = (s << 8) | (d & 255);
    }
}

__global__ __launch_bounds__(256) void bucket_csr_kernel(const int* __restrict__ ep,
                                                         const int* __restrict__ bucket_base,
                                                         int* __restrict__ row_start,
                                                         float* __restrict__ dinv,
                                                         int* __restrict__ src_sorted, int N, int E)
{
    __shared__ int h[256], sc[256], cur[256];
    int b = blockIdx.x;
    int tid = threadIdx.x;
    int e0 = bucket_base[b], e1 = bucket_base[b + 1];
    int node0 = b << BUCKET_SHIFT;
    int nn = min(256, N - node0);

    h[tid] = 0;
    __syncthreads();
    for (int e = e0 + tid; e < e1; e += 256)
        atomicAdd(&h[ep[e] & 255], 1);
    __syncthreads();

    sc[tid] = h[tid];
    __syncthreads();
    for (int off = 1; off < 256; off <<= 1) {
        int v = sc[tid];
        int add = (tid >= off) ? sc[tid - off] : 0;
        __syncthreads();
        sc[tid] = v + add;
        __syncthreads();
    }
    int excl = e0 + ((tid > 0) ? sc[tid - 1] : 0);
    if (tid < nn) {
        row_start[node0 + tid] = excl;
        dinv[node0 + tid] = rsqrtf((float)h[tid] + 1.0f);
    }
    cur[tid] = excl;
    __syncthreads();
    for (int e = e0 + tid; e < e1; e += 256) {
        int p = ep[e];
        int pos = atomicAdd(&cur[p & 255], 1);
        src_sorted[pos] = ((unsigned)p) >> 8;
    }
    if (b == 0 && tid == 0) row_start[N] = E;
}

// ---------------------------------------------------------------- weight pack (all 5 in one)
__global__ __launch_bounds__(256) void pack_all(
    const float* __restrict__ W1, const float* __restrict__ W2, const float* __restrict__ W3,
    const float* __restrict__ Wf1, const float* __restrict__ Wf2a,
    short* __restrict__ Wt1, short* __restrict__ Wt2, short* __restrict__ Wt3,
    short* __restrict__ Wtf1, short* __restrict__ Wtf2a)
{
    int idx = blockIdx.x * 256 + threadIdx.x;
    const float* W; short* Wt; int K, N, Kp, local;
    if (idx < 10400)       { W = W1;   Wt = Wt1;   K = 100; N = 100; Kp = 104; local = idx; }
    else if (idx < 20800)  { W = W2;   Wt = Wt2;   K = 100; N = 100; Kp = 104; local = idx - 10400; }
    else if (idx < 47424)  { W = W3;   Wt = Wt3;   K = 100; N = 256; Kp = 104; local = idx - 20800; }
    else if (idx < 112960) { W = Wf1;  Wt = Wtf1;  K = 256; N = 256; Kp = 256; local = idx - 47424; }
    else if (idx < 145728) { W = Wf2a; Wt = Wtf2a; K = 256; N = 128; Kp = 256; local = idx - 112960; }
    else return;
    int n = local / Kp, k = local - n * Kp;
    Wt[local] = (k < K) ? f2bf(W[(size_t)k * N + n]) : (short)0;
}

// ---------------------------------------------------------------- clip + fp32->bf16 cast of x
// One-shot: xc[r][0..99] = bf16(clip(x[r], -0.4, 0.4)), cols 100..103 = 0.
__global__ __launch_bounds__(256) void clip_cast_kernel(const float* __restrict__ x,
                                                        short* __restrict__ xc)
{
    int idx = blockIdx.x * 256 + threadIdx.x;   // one 8-col chunk per thread
    if (idx >= N_NODES * 13) return;
    int r = idx / 13, ch = idx - r * 13;
    int c8 = ch * 8;
    const float* xr = x + (size_t)r * F_IN_DIM + c8;
    float v[8];
    float4 v0 = *(const float4*)(xr);
    v[0] = v0.x; v[1] = v0.y; v[2] = v0.z; v[3] = v0.w;
    if (c8 < 96) {
        float4 v1 = *(const float4*)(xr + 4);
        v[4] = v1.x; v[5] = v1.y; v[6] = v1.z; v[7] = v1.w;
    } else {
        v[4] = v[5] = v[6] = v[7] = 0.f;     // pad cols 100..103
    }
    bf16x8 o;
    #pragma unroll
    for (int j = 0; j < 8; j++)
        o[j] = f2bf(fminf(fmaxf(v[j], -0.4f), 0.4f));
    *(bf16x8*)(xc + (size_t)r * F_IN_PAD + c8) = o;
}

// ---------------------------------------------------------------- one-shot MFMA GEMM (K=104, bf16)
// v2: A strip (128 rows x 104 shorts = 26KB, CONTIGUOUS since stride==row width) and
// B strip (26KB) staged via async global_load_lds: waves 0-1 stage A, waves 2-3 stage B,
// 13 x 1KB DMAs each, zero VGPR round-trip, zero guard branches (A padded to M_PAD rows;
// garbage pad rows/cols are masked by epilogue guards and zero-padded W K-rows).
// One barrier, MFMA, epilogue. LDS 53KB -> 3 blocks/CU.
__global__ __launch_bounds__(256) void gemm_oneshot(
    const short* __restrict__ A,     // [M_PAD][104] bf16
    const short* __restrict__ Wt,    // [>=colBase+128][104] bf16 (overread into ws is safe)
    const float* __restrict__ bias, const float* __restrict__ rowscale,
    short* __restrict__ C, int M, int Nout, int strideC, int relu)
{
    __shared__ __align__(16) short As[128 * F_IN_PAD];
    __shared__ __align__(16) short Bs[128 * F_IN_PAD];
    int tid = threadIdx.x;
    int wid = tid >> 6;
    int lane = tid & 63;
    int rowBase = blockIdx.x * 128;
    int colBase = blockIdx.y * 128;

    // ---- async stage: 26 chunks x 1KB per matrix
    {
        const short* gb = (wid < 2) ? (A + (size_t)rowBase * F_IN_PAD)
                                    : (Wt + (size_t)colBase * F_IN_PAD);
        short* lb = (wid < 2) ? As : Bs;
        int half = (wid & 1) * 13;
        #pragma unroll
        for (int i = 0; i < 13; i++) {
            int c = half + i;
            GLOAD_LDS16(gb + c * 512 + lane * 8, lb + c * 512);
        }
    }
    __syncthreads();   // the only barrier (drains the DMA queue)

    int quad = lane >> 4, l15 = lane & 15;
    int wave_m = (wid & 1) * 64;
    int wave_n = (wid >> 1) * 64;

    f32x4 acc[4][4];
    #pragma unroll
    for (int i = 0; i < 4; i++)
        #pragma unroll
        for (int j = 0; j < 4; j++)
            acc[i][j] = (f32x4){0.f, 0.f, 0.f, 0.f};

    #pragma unroll
    for (int kc = 0; kc < 4; kc++) {
        int off = kc * 32 + quad * 8;
        bool ok = (off + 8 <= F_IN_PAD);     // false only for kc=3, quad>=1 (pad)
        bf16x8 a[4], b[4];
        #pragma unroll
        for (int im = 0; im < 4; im++)
            a[im] = ok ? *(const bf16x8*)(As + (wave_m + im * 16 + l15) * F_IN_PAD + off)
                       : (bf16x8){0,0,0,0,0,0,0,0};
        #pragma unroll
        for (int in = 0; in < 4; in++)
            b[in] = ok ? *(const bf16x8*)(Bs + (wave_n + in * 16 + l15) * F_IN_PAD + off)
                       : (bf16x8){0,0,0,0,0,0,0,0};
        #pragma unroll
        for (int im = 0; im < 4; im++)
            #pragma unroll
            for (int in = 0; in < 4; in++)
                acc[im][in] = __builtin_amdgcn_mfma_f32_16x16x32_bf16(
                    a[im], b[in], acc[im][in], 0, 0, 0);
    }

    // ---- epilogue: C/D layout col=lane&15, row=quad*4+reg
    #pragma unroll
    for (int im = 0; im < 4; im++) {
        #pragma unroll
        for (int reg = 0; reg < 4; reg++) {
            int row = rowBase + wave_m + im * 16 + quad * 4 + reg;
            if (row >= M) continue;
            float rs = rowscale ? rowscale[row] : 1.f;
            #pragma unroll
            for (int in = 0; in < 4; in++) {
                int col = colBase + wave_n + in * 16 + l15;
                if (col >= strideC) continue;
                float v = 0.f;
                if (col < Nout) {
                    v = acc[im][in][reg];
                    if (bias) v += bias[col];
                    v *= rs;
                    if (relu) v = fmaxf(v, 0.f);
                }
                C[(size_t)row * strideC + col] = f2bf(v);
            }
        }
    }
}

// ---------------------------------------------------------------- fused fc1 + fc2a (v2, round-3 proven)
__global__ __launch_bounds__(512, 4) void fc_fused_kernel(
    const short* __restrict__ A,      // [M_PAD][256] bf16
    const short* __restrict__ W1t,    // [256][256] bf16, n-major
    const float* __restrict__ b1v,
    const short* __restrict__ W2t,    // [128][256] bf16, n-major
    const float* __restrict__ b2v,
    short* __restrict__ C)            // [M_PAD][128] bf16
{
    __shared__ __align__(16) short SB[128 * 256];   // 64 KB: As, then Hs (overwritten)
    int tid = threadIdx.x;
    int wid = tid >> 6;
    int lane = tid & 63;
    int quad = lane >> 4, l15 = lane & 15;
    int rowBase = blockIdx.x * 128;
    int xr = (l15 & 7) << 4;          // byte-XOR for this lane's rows (row&7 == l15&7)

    // ---- stage A strip: 64 chunks x 1KB, chunk c = rows {2c, 2c+1}; source pre-swizzled
    #pragma unroll
    for (int i = 0; i < 8; i++) {
        int c = i * 8 + wid;
        int r = c * 2 + (lane >> 5);
        int pb = ((lane & 31) * 16) ^ ((r & 7) << 4);   // swizzled byte-in-row
        const short* gp = A + (size_t)(rowBase + r) * H_DIM + (pb >> 1);
        GLOAD_LDS16(gp, SB + c * 512);
    }

    int wm = (wid & 1) * 64;          // GEMM1: 2M x 4N waves, 64x64 tile each
    int wn = (wid >> 1) * 64;

    f32x4 acc[4][4];
    #pragma unroll
    for (int i = 0; i < 4; i++)
        #pragma unroll
        for (int j = 0; j < 4; j++)
            acc[i][j] = (f32x4){0.f, 0.f, 0.f, 0.f};

    bf16x8 bA[4], bB[4];
    auto g1loadB = [&](bf16x8 (&dst)[4], int ks) {
        #pragma unroll
        for (int in = 0; in < 4; in++)
            dst[in] = *(const bf16x8*)(W1t + (size_t)(wn + in * 16 + l15) * H_DIM
                                       + ks * 32 + quad * 8);
    };
    auto g1step = [&](bf16x8 (&bc)[4], int ks) {
        bf16x8 a_[4];
        #pragma unroll
        for (int im = 0; im < 4; im++)
            a_[im] = *(const bf16x8*)(SB + (wm + im * 16 + l15) * 256
                                      + (((ks * 64 + quad * 16) ^ xr) >> 1));
        #pragma unroll
        for (int im = 0; im < 4; im++)
            #pragma unroll
            for (int in = 0; in < 4; in++)   // swapped: lane -> m=l15-based, 4 consecutive n
                acc[im][in] = __builtin_amdgcn_mfma_f32_16x16x32_bf16(
                    bc[in], a_[im], acc[im][in], 0, 0, 0);
    };

    g1loadB(bA, 0);        // prefetch ks=0 before the staging barrier
    __syncthreads();       // vmcnt(0): A staging complete

    g1loadB(bB, 1); g1step(bA, 0);
    g1loadB(bA, 2); g1step(bB, 1);
    g1loadB(bB, 3); g1step(bA, 2);
    g1loadB(bA, 4); g1step(bB, 3);
    g1loadB(bB, 5); g1step(bA, 4);
    g1loadB(bA, 6); g1step(bB, 5);
    g1loadB(bB, 7); g1step(bA, 6);
    g1step(bB, 7);

    // bias for swapped layout: n = wn + in*16 + quad*4 + reg
    float bb1[4][4];
    #pragma unroll
    for (int in = 0; in < 4; in++)
        #pragma unroll
        for (int r = 0; r < 4; r++)
            bb1[in][r] = b1v[wn + in * 16 + quad * 4 + r];

    __syncthreads();       // all waves done READING As -> safe to overwrite as Hs

    // GEMM2 prefetch (global, independent of LDS) issued before the Hs writes
    int wm2 = (wid & 1) * 64;         // GEMM2: 2M x 4N waves, 64x32 tile each
    int wn2 = (wid >> 1) * 32;
    bf16x8 cA[2], cB[2];
    auto g2loadB = [&](bf16x8 (&dst)[2], int ks) {
        #pragma unroll
        for (int in = 0; in < 2; in++)
            dst[in] = *(const bf16x8*)(W2t + (size_t)(wn2 + in * 16 + l15) * H_DIM
                                       + ks * 32 + quad * 8);
    };
    g2loadB(cA, 0);
    float bb2[2] = { b2v[wn2 + l15], b2v[wn2 + 16 + l15] };

    // ---- Hs write: relu(acc+b1) -> bf16, packed 4-consecutive-n b64, swizzled
    #pragma unroll
    for (int im = 0; im < 4; im++) {
        int ml = wm + im * 16 + l15;
        #pragma unroll
        for (int in = 0; in < 4; in++) {
            int nb = (wn + in * 16 + quad * 4) * 2;     // byte offset of col group
            s16x4 o = (s16x4){
                f2bf(fmaxf(acc[im][in][0] + bb1[in][0], 0.f)),
                f2bf(fmaxf(acc[im][in][1] + bb1[in][1], 0.f)),
                f2bf(fmaxf(acc[im][in][2] + bb1[in][2], 0.f)),
                f2bf(fmaxf(acc[im][in][3] + bb1[in][3], 0.f))};
            *(s16x4*)(SB + ml * 256 + ((nb ^ xr) >> 1)) = o;
        }
    }
    __syncthreads();       // Hs visible

    // ---- GEMM2: out = Hs @ W2 + b2 (unswapped; proven epilogue layout)
    f32x4 acc2[4][2];
    #pragma unroll
    for (int i = 0; i < 4; i++)
        #pragma unroll
        for (int j = 0; j < 2; j++)
            acc2[i][j] = (f32x4){0.f, 0.f, 0.f, 0.f};

    auto g2step = [&](bf16x8 (&bc)[2], int ks) {
        bf16x8 a_[4];
        #pragma unroll
        for (int im = 0; im < 4; im++)
            a_[im] = *(const bf16x8*)(SB + (wm2 + im * 16 + l15) * 256
                                      + (((ks * 64 + quad * 16) ^ xr) >> 1));
        #pragma unroll
        for (int im = 0; im < 4; im++)
            #pragma unroll
            for (int in = 0; in < 2; in++)
                acc2[im][in] = __builtin_amdgcn_mfma_f32_16x16x32_bf16(
                    a_[im], bc[in], acc2[im][in], 0, 0, 0);
    };

    g2loadB(cB, 1); g2step(cA, 0);
    g2loadB(cA, 2); g2step(cB, 1);
    g2loadB(cB, 3); g2step(cA, 2);
    g2loadB(cA, 4); g2step(cB, 3);
    g2loadB(cB, 5); g2step(cA, 4);
    g2loadB(cA, 6); g2step(cB, 5);
    g2loadB(cB, 7); g2step(cA, 6);
    g2step(cB, 7);

    // ---- epilogue: row = quad*4+reg (M), col = l15 (N); rows guard-free via M_PAD
    #pragma unroll
    for (int im = 0; im < 4; im++) {
        #pragma unroll
        for (int reg = 0; reg < 4; reg++) {
            int row = rowBase + wm2 + im * 16 + quad * 4 + reg;
            #pragma unroll
            for (int in = 0; in < 2; in++) {
                int col = wn2 + in * 16 + l15;
                C[(size_t)row * BN_DIM + col] = f2bf(acc2[im][in][reg] + bb2[in]);
            }
        }
    }
}

// ---------------------------------------------------------------- gather aggregation (bf16)
// v3 (round-3 proven, 68us): unroll x4, 2 accumulator chains, serial remainder.
// MODE 0: out = relu(di*(acc+self) + bias)           (conv1)
// MODE 1: out = di * relu(di*(acc+self) + bias)      (conv2: pre-folds next layer's dinv_s)
// MODE 2: out = di * (acc+self)                      (conv3 pre-aggregation)
template<int F, int STRIDE, int T, int MODE>
__global__ void gather_kernel(const short* __restrict__ xws,
                              const int* __restrict__ row_start,
                              const int* __restrict__ src_sorted,
                              const float* __restrict__ dinv,
                              const float* __restrict__ bias,
                              short* __restrict__ out, int n)
{
    constexpr int CHUNKS = STRIDE / 8;
    int group = (blockIdx.x * blockDim.x + threadIdx.x) / T;
    int lane = threadIdx.x % T;
    if (group >= n || lane >= CHUNKS) return;
    int d = group;
    int e0 = row_start[d], e1 = row_start[d + 1];
    int coff = lane * 8;
    const short* base = xws + coff;

    float acc[8] = {}, acc2[8] = {};
    int e = e0;
    for (; e + 3 < e1; e += 4) {
        int s0 = src_sorted[e + 0];
        int s1 = src_sorted[e + 1];
        int s2 = src_sorted[e + 2];
        int s3 = src_sorted[e + 3];
        bf16x8 v0 = *(const bf16x8*)(base + (size_t)s0 * STRIDE);
        bf16x8 v1 = *(const bf16x8*)(base + (size_t)s1 * STRIDE);
        bf16x8 v2 = *(const bf16x8*)(base + (size_t)s2 * STRIDE);
        bf16x8 v3 = *(const bf16x8*)(base + (size_t)s3 * STRIDE);
        #pragma unroll
        for (int j = 0; j < 8; j++) {
            acc[j]  += bf2f(v0[j]) + bf2f(v2[j]);
            acc2[j] += bf2f(v1[j]) + bf2f(v3[j]);
        }
    }
    for (; e < e1; e++) {
        int s = src_sorted[e];
        bf16x8 v = *(const bf16x8*)(base + (size_t)s * STRIDE);
        #pragma unroll
        for (int j = 0; j < 8; j++) acc[j] += bf2f(v[j]);
    }

    bf16x8 xv = *(const bf16x8*)(xws + (size_t)d * STRIDE + coff);
    float di = dinv[d];
    bf16x8 o;
    #pragma unroll
    for (int j = 0; j < 8; j++) {
        int col = coff + j;
        float v = 0.f;
        if (col < F) {
            v = di * (acc[j] + acc2[j] + bf2f(xv[j]));
            if (MODE == 0) v = fmaxf(v + bias[col], 0.f);
            if (MODE == 1) v = di * fmaxf(v + bias[col], 0.f);
        }
        o[j] = f2bf(v);
    }
    *(bf16x8*)(out + (size_t)d * STRIDE + coff) = o;
}

// ---------------------------------------------------------------- BN stats (bf16 input)
__global__ void bn_stats_kernel(const short* __restrict__ h,
                                float* __restrict__ sum, float* __restrict__ sumsq, int Ntot)
{
    int c = threadIdx.x & 127;
    int rpb = blockDim.x >> 7;
    int r0 = blockIdx.x * rpb + (threadIdx.x >> 7);
    int stride = gridDim.x * rpb;
    float s = 0.f, ss = 0.f;
    for (int r = r0; r < Ntot; r += stride) {
        float v = bf2f(h[(size_t)r * BN_DIM + c]);
        s += v; ss += v * v;
    }
    __shared__ float ls[256], lss[256];
    ls[threadIdx.x] = s; lss[threadIdx.x] = ss;
    __syncthreads();
    if (threadIdx.x < 128) {
        s = ls[threadIdx.x] + ls[threadIdx.x + 128];
        ss = lss[threadIdx.x] + lss[threadIdx.x + 128];
        atomicAdd(&sum[c], s);
        atomicAdd(&sumsq[c], ss);
    }
}

__global__ void bn_finalize_kernel(const float* __restrict__ sum, const float* __restrict__ sumsq,
                                   const float* __restrict__ gamma, const float* __restrict__ beta,
                                   float* __restrict__ a, float* __restrict__ b, int Ntot)
{
    int c = threadIdx.x;
    float inv_n = 1.0f / (float)Ntot;
    float mu = sum[c] * inv_n;
    float var = sumsq[c] * inv_n - mu * mu;
    float ai = gamma[c] * rsqrtf(var + BN_EPS);
    a[c] = ai;
    b[c] = beta[c] - mu * ai;
}

// ---------------------------------------------------------------- fused BN-apply + fc2b + log_softmax
__global__ __launch_bounds__(256) void fc2b_fused_kernel(
    const short* __restrict__ h, const float* __restrict__ bn_a, const float* __restrict__ bn_b,
    const float* __restrict__ W, const float* __restrict__ bias,
    float* __restrict__ out, int Ntot)
{
    __shared__ float Ws[BN_DIM][N_LABELS + 1];
    __shared__ float as[BN_DIM], bs[BN_DIM];
    for (int i = threadIdx.x; i < BN_DIM * N_LABELS; i += 256) {
        int k = i / N_LABELS, j = i - k * N_LABELS;
        Ws[k][j] = W[i];
    }
    if (threadIdx.x < BN_DIM) {
        as[threadIdx.x] = bn_a[threadIdx.x];
        bs[threadIdx.x] = bn_b[threadIdx.x];
    }
    __syncthreads();

    int r = blockIdx.x * 256 + threadIdx.x;
    if (r >= Ntot) return;

    float acc[N_LABELS];
    #pragma unroll
    for (int j = 0; j < N_LABELS; j++) acc[j] = bias[j];

    const short* hr = h + (size_t)r * BN_DIM;
    #pragma unroll
    for (int k0 = 0; k0 < BN_DIM; k0 += 8) {
        bf16x8 hv = *(const bf16x8*)(hr + k0);
        #pragma unroll
        for (int t = 0; t < 8; t++) {
            float v = fmaxf(bf2f(hv[t]) * as[k0 + t] + bs[k0 + t], 0.f);
            #pragma unroll
            for (int j = 0; j < N_LABELS; j++)
                acc[j] = fmaf(v, Ws[k0 + t][j], acc[j]);
        }
    }

    float m = acc[0];
    #pragma unroll
    for (int j = 1; j < N_LABELS; j++) m = fmaxf(m, acc[j]);
    float s = 0.f;
    #pragma unroll
    for (int j = 0; j < N_LABELS; j++) s += expf(acc[j] - m);
    float lse = m + logf(s);
    float* o = out + (size_t)r * N_LABELS;
    #pragma unroll
    for (int j = 0; j < N_LABELS; j++) o[j] = acc[j] - lse;
}

// ================================================================ launch
extern "C" void kernel_launch(void* const* d_in, const int* in_sizes, int n_in,
                              void* d_out, int out_size, void* d_ws, size_t ws_size,
                              hipStream_t stream)
{
    const float* x      = (const float*)d_in[0];
    const int*   ei     = (const int*)d_in[1];
    const float* W1     = (const float*)d_in[2];
    const float* b1     = (const float*)d_in[3];
    const float* W2     = (const float*)d_in[4];
    const float* b2     = (const float*)d_in[5];
    const float* W3     = (const float*)d_in[6];
    const float* b3     = (const float*)d_in[7];
    const float* fc1_W  = (const float*)d_in[8];
    const float* fc1_b  = (const float*)d_in[9];
    const float* fc2aW  = (const float*)d_in[10];
    const float* fc2ab  = (const float*)d_in[11];
    const float* gamma  = (const float*)d_in[12];
    const float* beta   = (const float*)d_in[13];
    const float* fc2bW  = (const float*)d_in[14];
    const float* fc2bb  = (const float*)d_in[15];
    float* out = (float*)d_out;

    const int* src = ei;
    const int* dst = ei + N_EDGES;

    char* w = (char*)d_ws;
    float* dinv        = (float*)w;  w += ((size_t)N_NODES * 4 + 255) / 256 * 256;
    int*   row_start   = (int*)w;    w += ((size_t)(N_NODES + 1) * 4 + 255) / 256 * 256;
    int*   part_hist   = (int*)w;    w += ((size_t)PB * NB * 4 + 255) / 256 * 256;
    int*   bucket_total= (int*)w;    w += ((size_t)NB * 4 + 255) / 256 * 256;
    int*   bucket_base = (int*)w;    w += ((size_t)(NB + 1) * 4 + 255) / 256 * 256;
    float* bn_sum      = (float*)w;  w += 128 * 4;
    float* bn_sumsq    = (float*)w;  w += 128 * 4;
    float* bn_a        = (float*)w;  w += 128 * 4;
    float* bn_b        = (float*)w;  w += 128 * 4;
    short* Wt1         = (short*)w;  w += ((size_t)F_IN_DIM * F_IN_PAD * 2 + 255) / 256 * 256;
    short* Wt2         = (short*)w;  w += ((size_t)F_IN_DIM * F_IN_PAD * 2 + 255) / 256 * 256;
    short* Wt3         = (short*)w;  w += ((size_t)H_DIM * F_IN_PAD * 2 + 255) / 256 * 256;
    short* Wtf1        = (short*)w;  w += ((size_t)H_DIM * H_DIM * 2 + 255) / 256 * 256;
    short* Wtf2a       = (short*)w;  w += ((size_t)BN_DIM * H_DIM * 2 + 255) / 256 * 256;
    int*   src_sorted  = (int*)w;    w += ((size_t)N_EDGES * 4 + 255) / 256 * 256;
    int*   ep          = (int*)w;    w += ((size_t)N_EDGES * 4 + 255) / 256 * 256;
    short* xws100      = (short*)w;  w += ((size_t)M_PAD * F_IN_PAD * 2 + 255) / 256 * 256;
    short* agg100      = (short*)w;  w += ((size_t)M_PAD * F_IN_PAD * 2 + 255) / 256 * 256;
    short* big1        = (short*)w;  w += ((size_t)M_PAD * H_DIM * 2 + 255) / 256 * 256;
    short* big2        = (short*)w;  w += ((size_t)M_PAD * H_DIM * 2 + 255) / 256 * 256;

    short* xclip = big1;   // [M_PAD][104] bf16, aliases big1 (dead until conv3 output)

    // ---- CSR build (bucket-partitioned, LDS atomics) + dinv
    part_hist_kernel<<<PB, 256, 0, stream>>>(dst, part_hist, N_EDGES);
    bucket_total_kernel<<<NB, 512, 0, stream>>>(part_hist, bucket_total);
    bucket_scan_kernel<<<1, 512, 0, stream>>>(bucket_total, bucket_base);
    part_offset_kernel<<<NB, 512, 0, stream>>>(part_hist, bucket_base);
    partition_kernel<<<PB, 256, 0, stream>>>(src, dst, part_hist, ep, N_EDGES);
    bucket_csr_kernel<<<NB, 256, 0, stream>>>(ep, bucket_base, row_start, dinv,
                                              src_sorted, N_NODES, N_EDGES);

    // ---- pack weights + clip/cast x
    pack_all<<<570, 256, 0, stream>>>(W1, W2, W3, fc1_W, fc2aW, Wt1, Wt2, Wt3, Wtf1, Wtf2a);
    clip_cast_kernel<<<(N_NODES * 13 + 255) / 256, 256, 0, stream>>>(x, xclip);

    const int nOne = (N_NODES + 127) / 128;   // 782
    int gatherBlocks = (N_NODES * 16 + 255) / 256;

    // ---- conv1: xw = xclip @ W1, rowscale dinv -> xws100; gather -> h1 (agg100)
    gemm_oneshot<<<dim3(nOne, 1), 256, 0, stream>>>(
        xclip, Wt1, nullptr, dinv, xws100, N_NODES, F_IN_DIM, F_IN_PAD, 0);
    gather_kernel<F_IN_DIM, F_IN_PAD, 16, 0><<<gatherBlocks, 256, 0, stream>>>(
        xws100, row_start, src_sorted, dinv, b1, agg100, N_NODES);

    // ---- conv2: xw = h1 @ W2, rowscale dinv -> xws100; gather (postscale dinv) -> h2' (agg100)
    gemm_oneshot<<<dim3(nOne, 1), 256, 0, stream>>>(
        agg100, Wt2, nullptr, dinv, xws100, N_NODES, F_IN_DIM, F_IN_PAD, 0);
    gather_kernel<F_IN_DIM, F_IN_PAD, 16, 1><<<gatherBlocks, 256, 0, stream>>>(
        xws100, row_start, src_sorted, dinv, b2, agg100, N_NODES);

    // ---- conv3 (aggregate-first): g = dinv_d*(sum h2' + self) -> xws100; h3 = relu(g@W3+b3) -> big1
    gather_kernel<F_IN_DIM, F_IN_PAD, 16, 2><<<gatherBlocks, 256, 0, stream>>>(
        agg100, row_start, src_sorted, dinv, nullptr, xws100, N_NODES);
    gemm_oneshot<<<dim3(nOne, 2), 256, 0, stream>>>(
        xws100, Wt3, b3, nullptr, big1, N_NODES, H_DIM, H_DIM, 1);

    // ---- fused fc1 (256->256, relu) + fc2a (256->128): big1 -> big2 [M_PAD][128]
    fc_fused_kernel<<<nOne, 512, 0, stream>>>(
        big1, Wtf1, fc1_b, Wtf2a, fc2ab, big2);

    // ---- BN stats (bf16 input)
    hipMemsetAsync(bn_sum, 0, 2 * 128 * 4, stream);
    bn_stats_kernel<<<512, 256, 0, stream>>>(big2, bn_sum, bn_sumsq, N_NODES);
    bn_finalize_kernel<<<1, 128, 0, stream>>>(bn_sum, bn_sumsq, gamma, beta, bn_a, bn_b, N_NODES);

    // ---- fused BN-apply + fc2b + log_softmax -> out
    fc2b_fused_kernel<<<(N_NODES + 255) / 256, 256, 0, stream>>>(
        big2, bn_a, bn_b, fc2bW, fc2bb, out, N_NODES);
}